// Round 1
// 1119.493 us; speedup vs baseline: 1.0115x; 1.0115x over previous
//
#include <hip/hip_runtime.h>
#include <hip/hip_bf16.h>

#define BB 8
#define CC 16
#define HH 128
#define WW 128
#define HD 64
#define WD 64
#define LP 4096
#define K1 144
#define KP 160
#define N2 256

typedef __attribute__((ext_vector_type(8))) short bf16x8;
typedef __attribute__((ext_vector_type(4))) float f32x4;

__device__ __forceinline__ unsigned short pack_rne(float x) {
    unsigned int u = __float_as_uint(x);
    return (unsigned short)((u + 0x7FFFu + ((u >> 16) & 1u)) >> 16);
}
__device__ __forceinline__ float bf2f(unsigned short u) {
    return __uint_as_float(((unsigned int)u) << 16);
}
__device__ __forceinline__ float ld_in(const void* p, long idx, int bf) {
    if (bf) return bf2f(((const unsigned short*)p)[idx]);
    return ((const float*)p)[idx];
}

// ---------------------------------------------------------------------------
__global__ void detect_kernel(const unsigned int* __restrict__ w, int* __restrict__ flag) {
    if (threadIdx.x == 0) {
        int cnt = 0;
        for (int i = 0; i < 256; i++) {
            unsigned int e = (w[i] >> 7) & 0xFF;
            if (e >= 100 && e <= 140) cnt++;
        }
        *flag = (cnt >= 192) ? 1 : 0;
    }
}

// ---------------------------------------------------------------------------
// prep: hi/lo bf16 split of Fgp and Kcols = bg/norm, zero-padded to KP;
// mmg[b,l] = mm.
// ---------------------------------------------------------------------------
__global__ __launch_bounds__(256) void prep_kernel(
    const void* __restrict__ fg, const void* __restrict__ bg,
    const void* __restrict__ mask, const int* __restrict__ flagp,
    unsigned short* __restrict__ Fh, unsigned short* __restrict__ Fl,
    unsigned short* __restrict__ Kh, unsigned short* __restrict__ Kl,
    float* __restrict__ mmg)
{
    int bf = *flagp;
    int bl = blockIdx.x;
    int b = bl >> 12, l = bl & 4095;
    int py = l >> 6, px = l & 63;
    int tid = threadIdx.x;
    __shared__ float sq[160];
    __shared__ float nrm_sh;

    float fgv = 0.f, bgv = 0.f;
    if (tid < K1) {
        int c = tid / 9;
        int r9 = tid - c * 9;
        int ky = r9 / 3, kx = r9 - ky * 3;
        int yy = py + ky - 1, xx = px + kx - 1;
        if (yy >= 0 && yy < HD && xx >= 0 && xx < WD) {
            long base = ((long)(b * CC + c) * HH + 2 * yy) * WW + 2 * xx;
            fgv = ld_in(fg, base, bf);
            bgv = ld_in(bg, base, bf);
        }
        sq[tid] = bgv * bgv;
    }
    __syncthreads();
    if (tid == 0) {
        float S = 0.f;
        for (int k = 0; k < K1; k++) S += sq[k];
        nrm_sh = fmaxf(sqrtf(S), 1e-4f);
    }
    __syncthreads();
    float nrm = nrm_sh;

    if (tid < KP) {
        long base = (long)bl * KP + tid;
        float kv = (tid < K1) ? (bgv / nrm) : 0.f;
        unsigned short fh = pack_rne(fgv);
        unsigned short fl = pack_rne(fgv - bf2f(fh));
        unsigned short kh = pack_rne(kv);
        unsigned short kl = pack_rne(kv - bf2f(kh));
        Fh[base] = fh; Fl[base] = fl;
        Kh[base] = kh; Kl[base] = kl;
    }
    if (tid == 0) {
        float s9 = 0.f;
        for (int ky = 0; ky < 3; ky++)
            for (int kx = 0; kx < 3; kx++) {
                int yy = py + ky - 1, xx = px + kx - 1;
                if (yy >= 0 && yy < HD && xx >= 0 && xx < WD)
                    s9 += ld_in(mask, ((long)b * HH + 2 * yy) * WW + 2 * xx, bf);
            }
        mmg[bl] = (s9 == 0.0f) ? 1.0f : 0.0f;
    }
}

// ---------------------------------------------------------------------------
__global__ __launch_bounds__(256) void vT_kernel(
    const void* __restrict__ bg, const int* __restrict__ flagp,
    unsigned short* __restrict__ VT)
{
    int bf = *flagp;
    int l0 = blockIdx.x * 16;
    int b = blockIdx.y;
    int j = threadIdx.x;
    int c = j >> 4, dy = (j >> 2) & 3, dx = j & 3;

    unsigned short buf[16];
#pragma unroll
    for (int i = 0; i < 16; i++) {
        int l = l0 + i;
        int ly = l >> 6, lx = l & 63;
        int Y = 2 * ly + dy - 1, X = 2 * lx + dx - 1;
        float v = 0.f;
        if (Y >= 0 && Y < HH && X >= 0 && X < WW)
            v = ld_in(bg, ((long)(b * CC + c) * HH + Y) * WW + X, bf);
        buf[i] = pack_rne(v);
    }
    uint4* dst = (uint4*)&VT[((size_t)(b * N2 + j)) * LP + l0];
    dst[0] = *(uint4*)&buf[0];
    dst[1] = *(uint4*)&buf[8];
}

// ---------------------------------------------------------------------------
__global__ __launch_bounds__(256) void zeroU_kernel(float4* __restrict__ U4) {
    U4[blockIdx.x * 256 + threadIdx.x] = make_float4(0.f, 0.f, 0.f, 0.f);
}

// ---------------------------------------------------------------------------
// gemmZ via split-bf16 MFMA (fp32-accurate), 128x64 tile, BK=32 (r18/r19).
// ---------------------------------------------------------------------------
__global__ __launch_bounds__(256) void gemmZ_mfma_kernel(
    const unsigned short* __restrict__ Ah, const unsigned short* __restrict__ Al,
    const unsigned short* __restrict__ Bh, const unsigned short* __restrict__ Bl,
    const float* __restrict__ mmv, float* __restrict__ Z)
{
    __shared__ unsigned short AhS[128][40];
    __shared__ unsigned short AlS[128][40];
    __shared__ unsigned short BhS[64][40];
    __shared__ unsigned short BlS[64][40];

    int t = threadIdx.x;
    int l0 = blockIdx.x * 64, p0 = blockIdx.y * 128;
    int wave = t >> 6, lane = t & 63;
    int lrow = lane & 15, lq = lane >> 4;

    f32x4 zero4 = {0.f, 0.f, 0.f, 0.f};
    f32x4 acc[2][4];
#pragma unroll
    for (int i = 0; i < 2; i++)
#pragma unroll
        for (int n = 0; n < 4; n++) acc[i][n] = zero4;

    int arow = t >> 1, ahalf = (t & 1) * 16;
    int brow = t >> 2, bq = (t & 3) * 8;

    for (int k0 = 0; k0 < KP; k0 += 32) {
        size_t abase = (size_t)(p0 + arow) * KP + k0 + ahalf;
        size_t bbase = (size_t)(l0 + brow) * KP + k0 + bq;
        uint4 ah0 = *(const uint4*)&Ah[abase];
        uint4 ah1 = *(const uint4*)&Ah[abase + 8];
        uint4 al0 = *(const uint4*)&Al[abase];
        uint4 al1 = *(const uint4*)&Al[abase + 8];
        uint4 bh0 = *(const uint4*)&Bh[bbase];
        uint4 bl0 = *(const uint4*)&Bl[bbase];
        __syncthreads();
        *(uint4*)&AhS[arow][ahalf] = ah0;
        *(uint4*)&AhS[arow][ahalf + 8] = ah1;
        *(uint4*)&AlS[arow][ahalf] = al0;
        *(uint4*)&AlS[arow][ahalf + 8] = al1;
        *(uint4*)&BhS[brow][bq] = bh0;
        *(uint4*)&BlS[brow][bq] = bl0;
        __syncthreads();

        bf16x8 ah[2], al[2], bh[4], blo[4];
#pragma unroll
        for (int i = 0; i < 2; i++) {
            ah[i] = *(const bf16x8*)&AhS[wave * 32 + i * 16 + lrow][lq * 8];
            al[i] = *(const bf16x8*)&AlS[wave * 32 + i * 16 + lrow][lq * 8];
        }
#pragma unroll
        for (int n = 0; n < 4; n++) {
            bh[n] = *(const bf16x8*)&BhS[n * 16 + lrow][lq * 8];
            blo[n] = *(const bf16x8*)&BlS[n * 16 + lrow][lq * 8];
        }
#pragma unroll
        for (int i = 0; i < 2; i++)
#pragma unroll
            for (int n = 0; n < 4; n++) {
                acc[i][n] = __builtin_amdgcn_mfma_f32_16x16x32_bf16(ah[i], bh[n], acc[i][n], 0, 0, 0);
                acc[i][n] = __builtin_amdgcn_mfma_f32_16x16x32_bf16(ah[i], blo[n], acc[i][n], 0, 0, 0);
                acc[i][n] = __builtin_amdgcn_mfma_f32_16x16x32_bf16(al[i], bh[n], acc[i][n], 0, 0, 0);
            }
    }

#pragma unroll
    for (int i = 0; i < 2; i++)
#pragma unroll
        for (int n = 0; n < 4; n++) {
            int row = p0 + wave * 32 + i * 16 + lq * 4;
            int col = l0 + n * 16 + lrow;
            float mmc = mmv[col];
#pragma unroll
            for (int r = 0; r < 4; r++) {
                float z = (mmc > 0.f) ? 10.0f * acc[i][n][r] : 0.f;
                Z[(size_t)(row + r) * LP + col] = z;
            }
        }
}

// ---------------------------------------------------------------------------
// statsW: softmax stats per row, then W[p,l] = bf16(exp(z-m)/denom * mm[l])
// in-place over the Z row prefix.
// ---------------------------------------------------------------------------
__global__ __launch_bounds__(256) void statsW_kernel(
    float* __restrict__ Z, const float* __restrict__ mmv)
{
    int p = blockIdx.x;
    int t = threadIdx.x;
    float4* Z4 = (float4*)(Z + (size_t)p * LP);
    __shared__ float red[256];

    float4 z[4];
    float mx = -1e30f;
#pragma unroll
    for (int i = 0; i < 4; i++) {
        z[i] = Z4[t + 256 * i];
        mx = fmaxf(mx, fmaxf(fmaxf(z[i].x, z[i].y), fmaxf(z[i].z, z[i].w)));
    }
    red[t] = mx;
    __syncthreads();
    for (int s = 128; s > 0; s >>= 1) {
        if (t < s) red[t] = fmaxf(red[t], red[t + s]);
        __syncthreads();
    }
    float m = red[0];
    __syncthreads();

    float4 e[4];
    float sum = 0.f;
#pragma unroll
    for (int i = 0; i < 4; i++) {
        e[i].x = expf(z[i].x - m);
        e[i].y = expf(z[i].y - m);
        e[i].z = expf(z[i].z - m);
        e[i].w = expf(z[i].w - m);
        sum += e[i].x + e[i].y + e[i].z + e[i].w;
    }
    red[t] = sum;
    __syncthreads();
    for (int s = 128; s > 0; s >>= 1) {
        if (t < s) red[t] += red[t + s];
        __syncthreads();
    }
    float dinv = 1.0f / red[0];

    const float4* mm4 = (const float4*)mmv;
    uint2* W2 = (uint2*)(Z + (size_t)p * LP);
#pragma unroll
    for (int i = 0; i < 4; i++) {
        float4 mm = mm4[t + 256 * i];
        uint2 pk;
        pk.x = (unsigned)pack_rne(e[i].x * dinv * mm.x) |
               ((unsigned)pack_rne(e[i].y * dinv * mm.y) << 16);
        pk.y = (unsigned)pack_rne(e[i].z * dinv * mm.z) |
               ((unsigned)pack_rne(e[i].w * dinv * mm.w) << 16);
        W2[t + 256 * i] = pk;
    }
}

// ---------------------------------------------------------------------------
// gemmU via bf16 MFMA, tile 64p x 256c, split-K=8 with fp32 atomics.
// v2: double-buffered LDS (2-phase pipeline, T3-min recipe), ONE barrier per
// K=32 step, reg-staged prefetch of the next tile issued before compute, and
// square-ish wave tiles (each wave 64 rows x 64 cols -> 8 ds_read_b128 per
// 16 MFMAs instead of 17).
// Grid (64 p-tiles, 8 kz). LDS: 2*(Ws 64x40 + Vs 256x40) = 51.2 KB.
// ---------------------------------------------------------------------------
__global__ __launch_bounds__(256) void gemmU_mfma_kernel(
    const unsigned short* __restrict__ W16,   // [4096][stride 8192]
    const unsigned short* __restrict__ VT,    // [256][4096]
    float* __restrict__ U)                    // [4096][256]
{
    __shared__ unsigned short Ws[2][64][40];
    __shared__ unsigned short Vs[2][256][40];

    int t = threadIdx.x;
    int p0 = blockIdx.x * 64;
    int kz = blockIdx.y;

    int wave = t >> 6, lane = t & 63;
    int lrow = lane & 15, lq = lane >> 4;

    f32x4 zero4 = {0.f, 0.f, 0.f, 0.f};
    f32x4 acc[4][4];
#pragma unroll
    for (int i = 0; i < 4; i++)
#pragma unroll
        for (int n = 0; n < 4; n++) acc[i][n] = zero4;

    int wrow = t >> 2, wq = (t & 3) * 8;   // loader: 64 rows x 4 k-octets

    const size_t wbase = (size_t)(p0 + wrow) * 8192 + (size_t)kz * 512 + wq;
    const size_t vbase = (size_t)wrow * LP + (size_t)kz * 512 + wq;

    // prologue: stage iter 0 into buf 0
    uint4 w0 = *(const uint4*)&W16[wbase];
    uint4 v0 = *(const uint4*)&VT[vbase];
    uint4 v1 = *(const uint4*)&VT[vbase + (size_t)64 * LP];
    uint4 v2 = *(const uint4*)&VT[vbase + (size_t)128 * LP];
    uint4 v3 = *(const uint4*)&VT[vbase + (size_t)192 * LP];
    *(uint4*)&Ws[0][wrow][wq] = w0;
    *(uint4*)&Vs[0][wrow][wq] = v0;
    *(uint4*)&Vs[0][wrow + 64][wq] = v1;
    *(uint4*)&Vs[0][wrow + 128][wq] = v2;
    *(uint4*)&Vs[0][wrow + 192][wq] = v3;
    __syncthreads();

    for (int it = 0; it < 16; ++it) {
        int cur = it & 1;
        if (it < 15) {
            size_t off = (size_t)(it + 1) * 32;
            w0 = *(const uint4*)&W16[wbase + off];
            v0 = *(const uint4*)&VT[vbase + off];
            v1 = *(const uint4*)&VT[vbase + (size_t)64 * LP + off];
            v2 = *(const uint4*)&VT[vbase + (size_t)128 * LP + off];
            v3 = *(const uint4*)&VT[vbase + (size_t)192 * LP + off];
        }

        bf16x8 a[4], b[4];
#pragma unroll
        for (int i = 0; i < 4; i++)
            a[i] = *(const bf16x8*)&Ws[cur][i * 16 + lrow][lq * 8];
#pragma unroll
        for (int n = 0; n < 4; n++)
            b[n] = *(const bf16x8*)&Vs[cur][wave * 64 + n * 16 + lrow][lq * 8];
#pragma unroll
        for (int i = 0; i < 4; i++)
#pragma unroll
            for (int n = 0; n < 4; n++)
                acc[i][n] = __builtin_amdgcn_mfma_f32_16x16x32_bf16(a[i], b[n], acc[i][n], 0, 0, 0);

        if (it < 15) {
            int nxt = cur ^ 1;
            *(uint4*)&Ws[nxt][wrow][wq] = w0;
            *(uint4*)&Vs[nxt][wrow][wq] = v0;
            *(uint4*)&Vs[nxt][wrow + 64][wq] = v1;
            *(uint4*)&Vs[nxt][wrow + 128][wq] = v2;
            *(uint4*)&Vs[nxt][wrow + 192][wq] = v3;
        }
        __syncthreads();
    }

#pragma unroll
    for (int i = 0; i < 4; i++)
#pragma unroll
        for (int n = 0; n < 4; n++) {
            int row = p0 + i * 16 + lq * 4;
            int col = wave * 64 + n * 16 + lrow;
#pragma unroll
            for (int r = 0; r < 4; r++)
                atomicAdd(&U[(size_t)(row + r) * N2 + col], acc[i][n][r]);
        }
}

// ---------------------------------------------------------------------------
// gather / overlap-add (upright), fp32 out
// ---------------------------------------------------------------------------
__global__ __launch_bounds__(256) void gather_kernel(
    const float* __restrict__ U, float* __restrict__ out)
{
    int idx = blockIdx.x * 256 + threadIdx.x;
    int ox = idx & 127;
    int t1 = idx >> 7;
    int oy = t1 & 127;
    int t2 = t1 >> 7;
    int c = t2 & 15;
    int b = t2 >> 4;

    float sum = 0.f;
    int d0y = (oy + 1) & 1, d0x = (ox + 1) & 1;
#pragma unroll
    for (int iy = 0; iy < 2; iy++) {
        int dy = d0y + 2 * iy;
        int y = (oy + 1 - dy) >> 1;
        if (y < 0 || y > 63) continue;
#pragma unroll
        for (int ix = 0; ix < 2; ix++) {
            int dx = d0x + 2 * ix;
            int x = (ox + 1 - dx) >> 1;
            if (x < 0 || x > 63) continue;
            sum += U[((long)b * LP + y * 64 + x) * N2 + c * 16 + dy * 4 + dx];
        }
    }
    out[idx] = sum * 0.25f;
}

// ---------------------------------------------------------------------------
extern "C" void kernel_launch(void* const* d_in, const int* in_sizes, int n_in,
                              void* d_out, int out_size, void* d_ws, size_t ws_size,
                              hipStream_t stream)
{
    const void* fg   = d_in[0];
    const void* bg   = d_in[1];
    const void* mask = d_in[2];
    float* out = (float*)d_out;

    char* w = (char*)d_ws;
    size_t o = 0;
    int*            flag = (int*)(w + o);            o += 16;
    unsigned short* Fh   = (unsigned short*)(w + o); o += (size_t)BB * LP * KP * 2;
    unsigned short* Fl   = (unsigned short*)(w + o); o += (size_t)BB * LP * KP * 2;
    unsigned short* Kh   = (unsigned short*)(w + o); o += (size_t)BB * LP * KP * 2;
    unsigned short* Kl   = (unsigned short*)(w + o); o += (size_t)BB * LP * KP * 2;
    unsigned short* VT   = (unsigned short*)(w + o); o += (size_t)BB * N2 * LP * 2;
    float*          U    = (float*)(w + o);          o += (size_t)BB * LP * N2 * 4;
    float*          mmg  = (float*)(w + o);          o += (size_t)BB * LP * 4;
    float*          Z    = (float*)(w + o);          o += (size_t)LP * LP * 4;

    detect_kernel<<<1, 64, 0, stream>>>((const unsigned int*)fg, flag);
    prep_kernel<<<BB * LP, 256, 0, stream>>>(fg, bg, mask, flag, Fh, Fl, Kh, Kl, mmg);
    vT_kernel<<<dim3(LP / 16, BB), 256, 0, stream>>>(bg, flag, VT);
    zeroU_kernel<<<(BB * LP * N2 / 4) / 256, 256, 0, stream>>>((float4*)U);

    for (int b = 0; b < BB; b++) {
        gemmZ_mfma_kernel<<<dim3(64, 32), 256, 0, stream>>>(
            Fh + (size_t)b * LP * KP, Fl + (size_t)b * LP * KP,
            Kh + (size_t)b * LP * KP, Kl + (size_t)b * LP * KP,
            mmg + (size_t)b * LP, Z);
        statsW_kernel<<<LP, 256, 0, stream>>>(Z, mmg + (size_t)b * LP);
        gemmU_mfma_kernel<<<dim3(64, 8), 256, 0, stream>>>(
            (const unsigned short*)Z, VT + (size_t)b * N2 * LP,
            U + (size_t)b * LP * N2);
    }

    gather_kernel<<<(BB * CC * HH * WW) / 256, 256, 0, stream>>>(U, out);
}

// Round 2
// 830.801 us; speedup vs baseline: 1.3630x; 1.3475x over previous
//
#include <hip/hip_runtime.h>
#include <hip/hip_bf16.h>

#define BB 8
#define CC 16
#define HH 128
#define WW 128
#define HD 64
#define WD 64
#define LP 4096
#define K1 144
#define KP 160
#define N2 256

typedef __attribute__((ext_vector_type(8))) short bf16x8;
typedef __attribute__((ext_vector_type(4))) float f32x4;

__device__ __forceinline__ unsigned short pack_rne(float x) {
    unsigned int u = __float_as_uint(x);
    return (unsigned short)((u + 0x7FFFu + ((u >> 16) & 1u)) >> 16);
}
__device__ __forceinline__ float bf2f(unsigned short u) {
    return __uint_as_float(((unsigned int)u) << 16);
}
__device__ __forceinline__ float ld_in(const void* p, long idx, int bf) {
    if (bf) return bf2f(((const unsigned short*)p)[idx]);
    return ((const float*)p)[idx];
}

// ---------------------------------------------------------------------------
__global__ void detect_kernel(const unsigned int* __restrict__ w, int* __restrict__ flag) {
    if (threadIdx.x == 0) {
        int cnt = 0;
        for (int i = 0; i < 256; i++) {
            unsigned int e = (w[i] >> 7) & 0xFF;
            if (e >= 100 && e <= 140) cnt++;
        }
        *flag = (cnt >= 192) ? 1 : 0;
    }
}

// ---------------------------------------------------------------------------
// prep: hi/lo bf16 split of Fgp and Kcols = bg/norm, zero-padded to KP;
// mmg[b,l] = mm.
// ---------------------------------------------------------------------------
__global__ __launch_bounds__(256) void prep_kernel(
    const void* __restrict__ fg, const void* __restrict__ bg,
    const void* __restrict__ mask, const int* __restrict__ flagp,
    unsigned short* __restrict__ Fh, unsigned short* __restrict__ Fl,
    unsigned short* __restrict__ Kh, unsigned short* __restrict__ Kl,
    float* __restrict__ mmg)
{
    int bf = *flagp;
    int bl = blockIdx.x;
    int b = bl >> 12, l = bl & 4095;
    int py = l >> 6, px = l & 63;
    int tid = threadIdx.x;
    __shared__ float sq[160];
    __shared__ float nrm_sh;

    float fgv = 0.f, bgv = 0.f;
    if (tid < K1) {
        int c = tid / 9;
        int r9 = tid - c * 9;
        int ky = r9 / 3, kx = r9 - ky * 3;
        int yy = py + ky - 1, xx = px + kx - 1;
        if (yy >= 0 && yy < HD && xx >= 0 && xx < WD) {
            long base = ((long)(b * CC + c) * HH + 2 * yy) * WW + 2 * xx;
            fgv = ld_in(fg, base, bf);
            bgv = ld_in(bg, base, bf);
        }
        sq[tid] = bgv * bgv;
    }
    __syncthreads();
    if (tid == 0) {
        float S = 0.f;
        for (int k = 0; k < K1; k++) S += sq[k];
        nrm_sh = fmaxf(sqrtf(S), 1e-4f);
    }
    __syncthreads();
    float nrm = nrm_sh;

    if (tid < KP) {
        long base = (long)bl * KP + tid;
        float kv = (tid < K1) ? (bgv / nrm) : 0.f;
        unsigned short fh = pack_rne(fgv);
        unsigned short fl = pack_rne(fgv - bf2f(fh));
        unsigned short kh = pack_rne(kv);
        unsigned short kl = pack_rne(kv - bf2f(kh));
        Fh[base] = fh; Fl[base] = fl;
        Kh[base] = kh; Kl[base] = kl;
    }
    if (tid == 0) {
        float s9 = 0.f;
        for (int ky = 0; ky < 3; ky++)
            for (int kx = 0; kx < 3; kx++) {
                int yy = py + ky - 1, xx = px + kx - 1;
                if (yy >= 0 && yy < HD && xx >= 0 && xx < WD)
                    s9 += ld_in(mask, ((long)b * HH + 2 * yy) * WW + 2 * xx, bf);
            }
        mmg[bl] = (s9 == 0.0f) ? 1.0f : 0.0f;
    }
}

// ---------------------------------------------------------------------------
__global__ __launch_bounds__(256) void vT_kernel(
    const void* __restrict__ bg, const int* __restrict__ flagp,
    unsigned short* __restrict__ VT)
{
    int bf = *flagp;
    int l0 = blockIdx.x * 16;
    int b = blockIdx.y;
    int j = threadIdx.x;
    int c = j >> 4, dy = (j >> 2) & 3, dx = j & 3;

    unsigned short buf[16];
#pragma unroll
    for (int i = 0; i < 16; i++) {
        int l = l0 + i;
        int ly = l >> 6, lx = l & 63;
        int Y = 2 * ly + dy - 1, X = 2 * lx + dx - 1;
        float v = 0.f;
        if (Y >= 0 && Y < HH && X >= 0 && X < WW)
            v = ld_in(bg, ((long)(b * CC + c) * HH + Y) * WW + X, bf);
        buf[i] = pack_rne(v);
    }
    uint4* dst = (uint4*)&VT[((size_t)(b * N2 + j)) * LP + l0];
    dst[0] = *(uint4*)&buf[0];
    dst[1] = *(uint4*)&buf[8];
}

// ---------------------------------------------------------------------------
// gemmZ via split-bf16 MFMA (fp32-accurate), 128x64 tile, BK=32 (r18/r19).
// ---------------------------------------------------------------------------
__global__ __launch_bounds__(256) void gemmZ_mfma_kernel(
    const unsigned short* __restrict__ Ah, const unsigned short* __restrict__ Al,
    const unsigned short* __restrict__ Bh, const unsigned short* __restrict__ Bl,
    const float* __restrict__ mmv, float* __restrict__ Z)
{
    __shared__ unsigned short AhS[128][40];
    __shared__ unsigned short AlS[128][40];
    __shared__ unsigned short BhS[64][40];
    __shared__ unsigned short BlS[64][40];

    int t = threadIdx.x;
    int l0 = blockIdx.x * 64, p0 = blockIdx.y * 128;
    int wave = t >> 6, lane = t & 63;
    int lrow = lane & 15, lq = lane >> 4;

    f32x4 zero4 = {0.f, 0.f, 0.f, 0.f};
    f32x4 acc[2][4];
#pragma unroll
    for (int i = 0; i < 2; i++)
#pragma unroll
        for (int n = 0; n < 4; n++) acc[i][n] = zero4;

    int arow = t >> 1, ahalf = (t & 1) * 16;
    int brow = t >> 2, bq = (t & 3) * 8;

    for (int k0 = 0; k0 < KP; k0 += 32) {
        size_t abase = (size_t)(p0 + arow) * KP + k0 + ahalf;
        size_t bbase = (size_t)(l0 + brow) * KP + k0 + bq;
        uint4 ah0 = *(const uint4*)&Ah[abase];
        uint4 ah1 = *(const uint4*)&Ah[abase + 8];
        uint4 al0 = *(const uint4*)&Al[abase];
        uint4 al1 = *(const uint4*)&Al[abase + 8];
        uint4 bh0 = *(const uint4*)&Bh[bbase];
        uint4 bl0 = *(const uint4*)&Bl[bbase];
        __syncthreads();
        *(uint4*)&AhS[arow][ahalf] = ah0;
        *(uint4*)&AhS[arow][ahalf + 8] = ah1;
        *(uint4*)&AlS[arow][ahalf] = al0;
        *(uint4*)&AlS[arow][ahalf + 8] = al1;
        *(uint4*)&BhS[brow][bq] = bh0;
        *(uint4*)&BlS[brow][bq] = bl0;
        __syncthreads();

        bf16x8 ah[2], al[2], bh[4], blo[4];
#pragma unroll
        for (int i = 0; i < 2; i++) {
            ah[i] = *(const bf16x8*)&AhS[wave * 32 + i * 16 + lrow][lq * 8];
            al[i] = *(const bf16x8*)&AlS[wave * 32 + i * 16 + lrow][lq * 8];
        }
#pragma unroll
        for (int n = 0; n < 4; n++) {
            bh[n] = *(const bf16x8*)&BhS[n * 16 + lrow][lq * 8];
            blo[n] = *(const bf16x8*)&BlS[n * 16 + lrow][lq * 8];
        }
#pragma unroll
        for (int i = 0; i < 2; i++)
#pragma unroll
            for (int n = 0; n < 4; n++) {
                acc[i][n] = __builtin_amdgcn_mfma_f32_16x16x32_bf16(ah[i], bh[n], acc[i][n], 0, 0, 0);
                acc[i][n] = __builtin_amdgcn_mfma_f32_16x16x32_bf16(ah[i], blo[n], acc[i][n], 0, 0, 0);
                acc[i][n] = __builtin_amdgcn_mfma_f32_16x16x32_bf16(al[i], bh[n], acc[i][n], 0, 0, 0);
            }
    }

#pragma unroll
    for (int i = 0; i < 2; i++)
#pragma unroll
        for (int n = 0; n < 4; n++) {
            int row = p0 + wave * 32 + i * 16 + lq * 4;
            int col = l0 + n * 16 + lrow;
            float mmc = mmv[col];
#pragma unroll
            for (int r = 0; r < 4; r++) {
                float z = (mmc > 0.f) ? 10.0f * acc[i][n][r] : 0.f;
                Z[(size_t)(row + r) * LP + col] = z;
            }
        }
}

// ---------------------------------------------------------------------------
// statsW: softmax stats per row, then W[p,l] = bf16(exp(z-m)/denom * mm[l])
// in-place over the Z row prefix.
// ---------------------------------------------------------------------------
__global__ __launch_bounds__(256) void statsW_kernel(
    float* __restrict__ Z, const float* __restrict__ mmv)
{
    int p = blockIdx.x;
    int t = threadIdx.x;
    float4* Z4 = (float4*)(Z + (size_t)p * LP);
    __shared__ float red[256];

    float4 z[4];
    float mx = -1e30f;
#pragma unroll
    for (int i = 0; i < 4; i++) {
        z[i] = Z4[t + 256 * i];
        mx = fmaxf(mx, fmaxf(fmaxf(z[i].x, z[i].y), fmaxf(z[i].z, z[i].w)));
    }
    red[t] = mx;
    __syncthreads();
    for (int s = 128; s > 0; s >>= 1) {
        if (t < s) red[t] = fmaxf(red[t], red[t + s]);
        __syncthreads();
    }
    float m = red[0];
    __syncthreads();

    float4 e[4];
    float sum = 0.f;
#pragma unroll
    for (int i = 0; i < 4; i++) {
        e[i].x = expf(z[i].x - m);
        e[i].y = expf(z[i].y - m);
        e[i].z = expf(z[i].z - m);
        e[i].w = expf(z[i].w - m);
        sum += e[i].x + e[i].y + e[i].z + e[i].w;
    }
    red[t] = sum;
    __syncthreads();
    for (int s = 128; s > 0; s >>= 1) {
        if (t < s) red[t] += red[t + s];
        __syncthreads();
    }
    float dinv = 1.0f / red[0];

    const float4* mm4 = (const float4*)mmv;
    uint2* W2 = (uint2*)(Z + (size_t)p * LP);
#pragma unroll
    for (int i = 0; i < 4; i++) {
        float4 mm = mm4[t + 256 * i];
        uint2 pk;
        pk.x = (unsigned)pack_rne(e[i].x * dinv * mm.x) |
               ((unsigned)pack_rne(e[i].y * dinv * mm.y) << 16);
        pk.y = (unsigned)pack_rne(e[i].z * dinv * mm.z) |
               ((unsigned)pack_rne(e[i].w * dinv * mm.w) << 16);
        W2[t + 256 * i] = pk;
    }
}

// ---------------------------------------------------------------------------
// gemmU via bf16 MFMA, tile 64p x 256c, split-K=8.
// v3: partials go to plain stores in U8[kz][4096][256] (disjoint tiles, no
// atomics -- the round-1 counters showed the atomicAdd epilogue (8.4M RMW
// atomics/dispatch) was ~85% of the kernel's time). reduceU sums the slabs.
// Double-buffered LDS, one barrier per K=32 step, 64x64 wave tiles.
// Grid (64 p-tiles, 8 kz). LDS: 2*(Ws 64x40 + Vs 256x40) = 51.2 KB.
// ---------------------------------------------------------------------------
__global__ __launch_bounds__(256) void gemmU_mfma_kernel(
    const unsigned short* __restrict__ W16,   // [4096][stride 8192]
    const unsigned short* __restrict__ VT,    // [256][4096]
    float* __restrict__ U8)                   // [8][4096][256]
{
    __shared__ unsigned short Ws[2][64][40];
    __shared__ unsigned short Vs[2][256][40];

    int t = threadIdx.x;
    int p0 = blockIdx.x * 64;
    int kz = blockIdx.y;

    int wave = t >> 6, lane = t & 63;
    int lrow = lane & 15, lq = lane >> 4;

    f32x4 zero4 = {0.f, 0.f, 0.f, 0.f};
    f32x4 acc[4][4];
#pragma unroll
    for (int i = 0; i < 4; i++)
#pragma unroll
        for (int n = 0; n < 4; n++) acc[i][n] = zero4;

    int wrow = t >> 2, wq = (t & 3) * 8;   // loader: 64 rows x 4 k-octets

    const size_t wbase = (size_t)(p0 + wrow) * 8192 + (size_t)kz * 512 + wq;
    const size_t vbase = (size_t)wrow * LP + (size_t)kz * 512 + wq;

    // prologue: stage iter 0 into buf 0
    uint4 w0 = *(const uint4*)&W16[wbase];
    uint4 v0 = *(const uint4*)&VT[vbase];
    uint4 v1 = *(const uint4*)&VT[vbase + (size_t)64 * LP];
    uint4 v2 = *(const uint4*)&VT[vbase + (size_t)128 * LP];
    uint4 v3 = *(const uint4*)&VT[vbase + (size_t)192 * LP];
    *(uint4*)&Ws[0][wrow][wq] = w0;
    *(uint4*)&Vs[0][wrow][wq] = v0;
    *(uint4*)&Vs[0][wrow + 64][wq] = v1;
    *(uint4*)&Vs[0][wrow + 128][wq] = v2;
    *(uint4*)&Vs[0][wrow + 192][wq] = v3;
    __syncthreads();

    for (int it = 0; it < 16; ++it) {
        int cur = it & 1;
        if (it < 15) {
            size_t off = (size_t)(it + 1) * 32;
            w0 = *(const uint4*)&W16[wbase + off];
            v0 = *(const uint4*)&VT[vbase + off];
            v1 = *(const uint4*)&VT[vbase + (size_t)64 * LP + off];
            v2 = *(const uint4*)&VT[vbase + (size_t)128 * LP + off];
            v3 = *(const uint4*)&VT[vbase + (size_t)192 * LP + off];
        }

        bf16x8 a[4], b[4];
#pragma unroll
        for (int i = 0; i < 4; i++)
            a[i] = *(const bf16x8*)&Ws[cur][i * 16 + lrow][lq * 8];
#pragma unroll
        for (int n = 0; n < 4; n++)
            b[n] = *(const bf16x8*)&Vs[cur][wave * 64 + n * 16 + lrow][lq * 8];
#pragma unroll
        for (int i = 0; i < 4; i++)
#pragma unroll
            for (int n = 0; n < 4; n++)
                acc[i][n] = __builtin_amdgcn_mfma_f32_16x16x32_bf16(a[i], b[n], acc[i][n], 0, 0, 0);

        if (it < 15) {
            int nxt = cur ^ 1;
            *(uint4*)&Ws[nxt][wrow][wq] = w0;
            *(uint4*)&Vs[nxt][wrow][wq] = v0;
            *(uint4*)&Vs[nxt][wrow + 64][wq] = v1;
            *(uint4*)&Vs[nxt][wrow + 128][wq] = v2;
            *(uint4*)&Vs[nxt][wrow + 192][wq] = v3;
        }
        __syncthreads();
    }

    float* Uo = U8 + (size_t)kz * LP * N2;
#pragma unroll
    for (int i = 0; i < 4; i++)
#pragma unroll
        for (int n = 0; n < 4; n++) {
            int row = p0 + i * 16 + lq * 4;
            int col = wave * 64 + n * 16 + lrow;
#pragma unroll
            for (int r = 0; r < 4; r++)
                Uo[(size_t)(row + r) * N2 + col] = acc[i][n][r];
        }
}

// ---------------------------------------------------------------------------
// reduceU: U[b] = sum_kz U8[kz]; pure HBM streaming (32 MB read, 4 MB write).
// ---------------------------------------------------------------------------
__global__ __launch_bounds__(256) void reduceU_kernel(
    const float4* __restrict__ U8, float4* __restrict__ U)
{
    int i = blockIdx.x * 256 + threadIdx.x;
    float4 s = U8[i];
#pragma unroll
    for (int k = 1; k < 8; k++) {
        float4 v = U8[(size_t)k * (LP * N2 / 4) + i];
        s.x += v.x; s.y += v.y; s.z += v.z; s.w += v.w;
    }
    U[i] = s;
}

// ---------------------------------------------------------------------------
// gather / overlap-add (upright), fp32 out
// ---------------------------------------------------------------------------
__global__ __launch_bounds__(256) void gather_kernel(
    const float* __restrict__ U, float* __restrict__ out)
{
    int idx = blockIdx.x * 256 + threadIdx.x;
    int ox = idx & 127;
    int t1 = idx >> 7;
    int oy = t1 & 127;
    int t2 = t1 >> 7;
    int c = t2 & 15;
    int b = t2 >> 4;

    float sum = 0.f;
    int d0y = (oy + 1) & 1, d0x = (ox + 1) & 1;
#pragma unroll
    for (int iy = 0; iy < 2; iy++) {
        int dy = d0y + 2 * iy;
        int y = (oy + 1 - dy) >> 1;
        if (y < 0 || y > 63) continue;
#pragma unroll
        for (int ix = 0; ix < 2; ix++) {
            int dx = d0x + 2 * ix;
            int x = (ox + 1 - dx) >> 1;
            if (x < 0 || x > 63) continue;
            sum += U[((long)b * LP + y * 64 + x) * N2 + c * 16 + dy * 4 + dx];
        }
    }
    out[idx] = sum * 0.25f;
}

// ---------------------------------------------------------------------------
extern "C" void kernel_launch(void* const* d_in, const int* in_sizes, int n_in,
                              void* d_out, int out_size, void* d_ws, size_t ws_size,
                              hipStream_t stream)
{
    const void* fg   = d_in[0];
    const void* bg   = d_in[1];
    const void* mask = d_in[2];
    float* out = (float*)d_out;

    char* w = (char*)d_ws;
    size_t o = 0;
    int*            flag = (int*)(w + o);            o += 16;
    unsigned short* Fh   = (unsigned short*)(w + o); o += (size_t)BB * LP * KP * 2;
    unsigned short* Fl   = (unsigned short*)(w + o); o += (size_t)BB * LP * KP * 2;
    unsigned short* Kh   = (unsigned short*)(w + o); o += (size_t)BB * LP * KP * 2;
    unsigned short* Kl   = (unsigned short*)(w + o); o += (size_t)BB * LP * KP * 2;
    unsigned short* VT   = (unsigned short*)(w + o); o += (size_t)BB * N2 * LP * 2;
    float*          U    = (float*)(w + o);          o += (size_t)BB * LP * N2 * 4;
    float*          mmg  = (float*)(w + o);          o += (size_t)BB * LP * 4;
    float*          Z    = (float*)(w + o);          o += (size_t)LP * LP * 4;
    float*          U8   = (float*)(w + o);          o += (size_t)8 * LP * N2 * 4;

    detect_kernel<<<1, 64, 0, stream>>>((const unsigned int*)fg, flag);
    prep_kernel<<<BB * LP, 256, 0, stream>>>(fg, bg, mask, flag, Fh, Fl, Kh, Kl, mmg);
    vT_kernel<<<dim3(LP / 16, BB), 256, 0, stream>>>(bg, flag, VT);

    for (int b = 0; b < BB; b++) {
        gemmZ_mfma_kernel<<<dim3(64, 32), 256, 0, stream>>>(
            Fh + (size_t)b * LP * KP, Fl + (size_t)b * LP * KP,
            Kh + (size_t)b * LP * KP, Kl + (size_t)b * LP * KP,
            mmg + (size_t)b * LP, Z);
        statsW_kernel<<<LP, 256, 0, stream>>>(Z, mmg + (size_t)b * LP);
        gemmU_mfma_kernel<<<dim3(64, 8), 256, 0, stream>>>(
            (const unsigned short*)Z, VT + (size_t)b * N2 * LP, U8);
        reduceU_kernel<<<LP * N2 / 4 / 256, 256, 0, stream>>>(
            (const float4*)U8, (float4*)(U + (size_t)b * LP * N2));
    }

    gather_kernel<<<(BB * CC * HH * WW) / 256, 256, 0, stream>>>(U, out);
}